// Round 10
// baseline (520.329 us; speedup 1.0000x reference)
//
#include <hip/hip_runtime.h>
#include <math.h>

#define NND 50000
#define HD  128
#define NE  800000
#define NBK 196          // buckets of 256 nodes: col>>8, max 195
#define BINB 391         // ceil(NE/2048)
#define NCH 391          // 50048/128 row chunks for k_mm

typedef unsigned short u16;
typedef unsigned int   u32;
typedef __attribute__((ext_vector_type(8))) short bf16x8;
typedef __attribute__((ext_vector_type(4))) float f32x4;

__device__ __forceinline__ float bf2f(u32 u) {
  union { u32 i; float f; } v; v.i = u << 16; return v.f;
}
__device__ __forceinline__ u16 f2bf(float f) {
  union { float f; u32 i; } v; v.f = f;
  return (u16)((v.i + 0x7FFFu + ((v.i >> 16) & 1u)) >> 16);
}
__device__ __forceinline__ void unpack8(uint4 m, float* f) {
  f[0] = bf2f(m.x & 0xFFFFu); f[1] = bf2f(m.x >> 16);
  f[2] = bf2f(m.y & 0xFFFFu); f[3] = bf2f(m.y >> 16);
  f[4] = bf2f(m.z & 0xFFFFu); f[5] = bf2f(m.z >> 16);
  f[6] = bf2f(m.w & 0xFFFFu); f[7] = bf2f(m.w >> 16);
}

// ---------------- fused: bucket histogram + weight prep ----------------
// blocks [0,BINB): histogram of col>>8. blocks [BINB,BINB+256): transposed bf16 hi/lo weights,
// LDS-swizzled layout: element (n,k) at u16-index n*128 + ((k>>3 ^ (n&7))<<3) + (k&7)
__global__ __launch_bounds__(256) void k_prep(const int* __restrict__ col, u32* __restrict__ bhist,
                                              const float* __restrict__ W1, const float* __restrict__ W2,
                                              const float* __restrict__ We1,
                                              u16* __restrict__ t1h, u16* __restrict__ t1l,
                                              u16* __restrict__ t2h, u16* __restrict__ t2l,
                                              u16* __restrict__ teh, u16* __restrict__ tel) {
  __shared__ u32 lh[NBK];
  int tid = threadIdx.x;
  if (blockIdx.x < BINB) {
    if (tid < NBK) lh[tid] = 0;
    __syncthreads();
    int e0 = blockIdx.x * 2048;
    #pragma unroll
    for (int s = 0; s < 8; ++s) {
      int e = e0 + s * 256 + tid;
      if (e < NE) atomicAdd(&lh[col[e] >> 8], 1u);
    }
    __syncthreads();
    if (tid < NBK && lh[tid]) atomicAdd(&bhist[tid], lh[tid]);
    return;
  }
  int idx = (blockIdx.x - BINB) * 256 + tid;   // 65536 total
  float w;
  u16 *dh, *dl;
  int j;
  if (idx < 16384) {
    j = idx; int n = j >> 7, k = j & 127;
    w = W1[k * 128 + n]; dh = t1h; dl = t1l;
  } else if (idx < 32768) {
    j = idx - 16384; int n = j >> 7, k = j & 127;
    w = W2[k * 128 + n]; dh = t2h; dl = t2l;
  } else {
    j = idx - 32768; int n = j >> 7, k = j & 127;
    w = (n < 128) ? We1[k * 128 + n] : We1[(128 + k) * 128 + (n - 128)];
    dh = teh; dl = tel;
  }
  int n = j >> 7, k = j & 127;
  int sidx = n * 128 + ((((k >> 3) ^ (n & 7))) << 3) + (k & 7);
  u16 hi = f2bf(w);
  float res = w - bf2f((u32)hi);
  dh[sidx] = hi;
  dl[sidx] = f2bf(res);
}

// ---------------- scan bucket counts -> bbase, bcur ----------------
__global__ __launch_bounds__(256) void k_bscan(const u32* __restrict__ bhist, u32* __restrict__ bbase,
                                               u32* __restrict__ bcur) {
  __shared__ u32 ws[4];
  int tid = threadIdx.x, lane = tid & 63, wid = tid >> 6;
  u32 d = (tid < NBK) ? bhist[tid] : 0;
  u32 x = d;
  #pragma unroll
  for (int off = 1; off < 64; off <<= 1) {
    u32 y = __shfl_up(x, off);
    if (lane >= off) x += y;
  }
  if (lane == 63) ws[wid] = x;
  __syncthreads();
  u32 woff = 0;
  for (int w = 0; w < wid; ++w) woff += ws[w];
  if (tid < NBK) { bbase[tid] = woff + x - d; bcur[tid] = woff + x - d; }
}

// ---------------- binning: block-aggregated contiguous reservations per bucket --------
// record: x = row | ((col&255)<<16), y = eid
__global__ __launch_bounds__(256) void k_bin(const int* __restrict__ row, const int* __restrict__ col,
                                             u32* __restrict__ bcur, uint2* __restrict__ recs) {
  __shared__ u32 lcount[NBK], lbase[NBK];
  int tid = threadIdx.x;
  if (tid < NBK) lcount[tid] = 0;
  __syncthreads();
  int e0 = blockIdx.x * 2048;
  u32 rank[8]; int cv[8];
  #pragma unroll
  for (int s = 0; s < 8; ++s) {
    int e = e0 + s * 256 + tid;
    if (e < NE) {
      cv[s] = col[e];
      rank[s] = atomicAdd(&lcount[cv[s] >> 8], 1u);
    }
  }
  __syncthreads();
  if (tid < NBK && lcount[tid]) lbase[tid] = atomicAdd(&bcur[tid], lcount[tid]);
  __syncthreads();
  #pragma unroll
  for (int s = 0; s < 8; ++s) {
    int e = e0 + s * 256 + tid;
    if (e < NE) {
      int c = cv[s];
      u32 slot = lbase[c >> 8] + rank[s];
      recs[slot] = make_uint2((u32)row[e] | (((u32)c & 255u) << 16), (u32)e);
    }
  }
}

// ---------------- fine sort within bucket; emits sre (row | col<<16, eid), ptr, dinv, dhist ------
__global__ __launch_bounds__(256) void k_fine(const u32* __restrict__ bhist, const u32* __restrict__ bbase,
                                              const uint2* __restrict__ recs, uint2* __restrict__ sre,
                                              int* __restrict__ ptr, float* __restrict__ dinv,
                                              u32* __restrict__ dhist) {
  __shared__ u32 lh[256];
  __shared__ u32 ws[4];
  int b = blockIdx.x, tid = threadIdx.x, lane = tid & 63, wid = tid >> 6;
  u32 base = bbase[b], cnt = bhist[b];
  lh[tid] = 0;
  __syncthreads();
  for (u32 i = tid; i < cnt; i += 256) atomicAdd(&lh[(recs[base + i].x >> 16) & 255u], 1u);
  __syncthreads();
  u32 ci = lh[tid];
  u32 x = ci;
  #pragma unroll
  for (int off = 1; off < 64; off <<= 1) {
    u32 y = __shfl_up(x, off);
    if (lane >= off) x += y;
  }
  if (lane == 63) ws[wid] = x;
  __syncthreads();
  u32 woff = 0;
  for (int w = 0; w < wid; ++w) woff += ws[w];
  u32 excl = woff + x - ci;
  int node = b * 256 + tid;
  if (node <= NND) ptr[node] = (int)(base + excl);
  if (node < NND) {
    dinv[node] = rsqrtf((float)(ci + 1));
    atomicAdd(&dhist[ci < 63u ? ci : 63u], 1u);
  }
  __syncthreads();
  lh[tid] = excl;                 // cursors
  __syncthreads();
  for (u32 i = tid; i < cnt; i += 256) {
    uint2 rec = recs[base + i];
    u32 cidx = (rec.x >> 16) & 255u;
    u32 r = atomicAdd(&lh[cidx], 1u);
    sre[base + r] = make_uint2((rec.x & 0xFFFFu) | (((u32)b * 256u + cidx) << 16), rec.y);
  }
}

// ---------------- degree-bin suffix scan (descending degree order) ----------------
__global__ __launch_bounds__(64) void k_dscan(const u32* __restrict__ dhist, u32* __restrict__ dcur) {
  int lane = threadIdx.x;                // 0..63
  u32 d = dhist[lane];
  u32 x = d;
  #pragma unroll
  for (int off = 1; off < 64; off <<= 1) {
    u32 y = __shfl_down(x, off);
    if (lane + off < 64) x += y;
  }
  dcur[lane] = x - d;                    // start = sum of higher-degree bins
}

// ---------------- perm: nodes in descending-degree-bin order ----------------
__global__ __launch_bounds__(256) void k_dplace(const int* __restrict__ ptr, u32* __restrict__ dcur,
                                                int* __restrict__ perm) {
  int v = blockIdx.x * 256 + threadIdx.x;
  if (v >= NND) return;
  int d = ptr[v + 1] - ptr[v];
  int b = d < 63 ? d : 63;
  u32 slot = atomicAdd(&dcur[b], 1u);
  perm[slot] = v;
}

// ---------------- persistent-W MFMA GEMM, one 128-row chunk per block ----------------
// OUT[r][h*128+n] = bf16( (X[r][:] . Wt_h[n][:]) * (scale?scale[r]:1) + (bias&&h ? bias[n] : 0) )
__device__ __forceinline__ void mm_body(const void* Xv, bool afp32,
                                        const u16* Whi, const u16* Wlo,
                                        u16* OUT, const float* scale, int ostride,
                                        const float* bias) {
  __shared__ __align__(16) u16 Bh[128 * 128];   // 32 KB
  __shared__ __align__(16) u16 Bl[128 * 128];   // 32 KB
  int tid = threadIdx.x;
  int h = blockIdx.x / NCH;
  int chunk = blockIdx.x - h * NCH;
  Whi += (size_t)h * 128 * 128;
  Wlo += (size_t)h * 128 * 128;
  int ooff = h * 128;
  {
    const uint4* gh = (const uint4*)Whi;
    const uint4* gl = (const uint4*)Wlo;
    uint4* lh = (uint4*)Bh;
    uint4* ll = (uint4*)Bl;
    #pragma unroll
    for (int i = 0; i < 4; ++i) {
      lh[tid + i * 512] = gh[tid + i * 512];
      ll[tid + i * 512] = gl[tid + i * 512];
    }
  }
  __syncthreads();
  int wid = tid >> 6, lane = tid & 63;
  int m16 = lane & 15, kg = lane >> 4;
  int arow = chunk * 128 + wid * 16 + m16;
  int ar = (arow < NND) ? arow : NND - 1;        // clamp: garbage stays in unstored D rows
  bf16x8 afrag[4];
  if (afp32) {
    const float* X = (const float*)Xv + (size_t)ar * 128 + kg * 8;
    #pragma unroll
    for (int ks = 0; ks < 4; ++ks) {
      float4 a = *(const float4*)(X + ks * 32);
      float4 b = *(const float4*)(X + ks * 32 + 4);
      union { u32 w[4]; bf16x8 v; } u;
      u.w[0] = (u32)f2bf(a.x) | ((u32)f2bf(a.y) << 16);
      u.w[1] = (u32)f2bf(a.z) | ((u32)f2bf(a.w) << 16);
      u.w[2] = (u32)f2bf(b.x) | ((u32)f2bf(b.y) << 16);
      u.w[3] = (u32)f2bf(b.z) | ((u32)f2bf(b.w) << 16);
      afrag[ks] = u.v;
    }
  } else {
    const u16* X = (const u16*)Xv + (size_t)ar * 128 + kg * 8;
    #pragma unroll
    for (int ks = 0; ks < 4; ++ks) afrag[ks] = *(const bf16x8*)(X + ks * 32);
  }
  int crow0 = chunk * 128 + wid * 16 + kg * 4;   // C/D: row=(lane>>4)*4+reg, col=lane&15
  float sc[4];
  #pragma unroll
  for (int j = 0; j < 4; ++j)
    sc[j] = (scale != nullptr && crow0 + j < NND) ? scale[crow0 + j] : 1.0f;
  #pragma unroll
  for (int t = 0; t < 8; ++t) {
    int coln = t * 16 + m16;
    float badd = (bias != nullptr && h != 0) ? bias[coln] : 0.f;
    f32x4 acc = {0.f, 0.f, 0.f, 0.f};
    #pragma unroll
    for (int ks = 0; ks < 4; ++ks) {
      int c8 = (ks * 4 + kg) ^ (coln & 7);
      bf16x8 bhf = *(const bf16x8*)(Bh + coln * 128 + c8 * 8);
      bf16x8 blf = *(const bf16x8*)(Bl + coln * 128 + c8 * 8);
      acc = __builtin_amdgcn_mfma_f32_16x16x32_bf16(afrag[ks], bhf, acc, 0, 0, 0);
      acc = __builtin_amdgcn_mfma_f32_16x16x32_bf16(afrag[ks], blf, acc, 0, 0, 0);
    }
    #pragma unroll
    for (int j = 0; j < 4; ++j) {
      int r = crow0 + j;
      if (r < NND) OUT[(size_t)r * ostride + ooff + coln] = f2bf(acc[j] * sc[j] + badd);
    }
  }
}

template<bool AFP32>
__global__ __launch_bounds__(512) void k_mm(const void* __restrict__ Xv,
                                            const u16* __restrict__ Whi, const u16* __restrict__ Wlo,
                                            u16* __restrict__ OUT, const float* __restrict__ scale,
                                            int ostride, const float* __restrict__ bias) {
  mm_body(Xv, AFP32, Whi, Wlo, OUT, scale, ostride, bias);
}

// ---------------- gather-aggregate: one NODE per wave64 (degree-sorted perm order) ----------
__global__ __launch_bounds__(256) void k_gather(const int* __restrict__ ptr, const uint2* __restrict__ sre,
                                                const int* __restrict__ perm,
                                                const float* __restrict__ dinv, const u16* __restrict__ Ts,
                                                u16* __restrict__ H, const float* __restrict__ bias) {
  int wid = threadIdx.x >> 6, lane = threadIdx.x & 63;
  int ch8 = lane & 15, slot = lane >> 4;
  int idx = blockIdx.x * 4 + wid; if (idx >= NND) return;
  int v = perm[idx];
  int p0 = ptr[v], p1 = ptr[v + 1];
  const uint4* T4 = (const uint4*)Ts;            // row = 16 uint4
  float acc[8];
  if (slot == 0) {
    uint4 m = T4[(size_t)v * 16 + ch8];          // self-loop (Ts pre-scaled by dinv[src])
    unpack8(m, acc);
  } else {
    #pragma unroll
    for (int k = 0; k < 8; ++k) acc[k] = 0.f;
  }
  for (int j2 = p0; j2 < p1; j2 += 32) {
    bool ok[8]; int r[8];
    #pragma unroll
    for (int u = 0; u < 8; ++u) {
      int j = j2 + u * 4 + slot;
      ok[u] = j < p1;
      r[u] = (int)(sre[ok[u] ? j : p0].x & 0xFFFFu);
    }
    uint4 m[8];
    #pragma unroll
    for (int u = 0; u < 8; ++u) m[u] = T4[(size_t)r[u] * 16 + ch8];
    #pragma unroll
    for (int u = 0; u < 8; ++u) {
      if (ok[u]) {
        float f[8]; unpack8(m[u], f);
        #pragma unroll
        for (int k = 0; k < 8; ++k) acc[k] += f[k];
      }
    }
  }
  #pragma unroll
  for (int k = 0; k < 8; ++k) {
    acc[k] += __shfl_xor(acc[k], 16);
    acc[k] += __shfl_xor(acc[k], 32);
  }
  if (slot == 0) {
    float s = dinv[v];
    float4 ba = *(const float4*)(bias + ch8 * 8);
    float4 bb = *(const float4*)(bias + ch8 * 8 + 4);
    float bv[8] = {ba.x, ba.y, ba.z, ba.w, bb.x, bb.y, bb.z, bb.w};
    u32 pk[4];
    #pragma unroll
    for (int k = 0; k < 4; ++k) {
      float o0 = fmaxf(fmaf(acc[2 * k], s, bv[2 * k]), 0.f);
      float o1 = fmaxf(fmaf(acc[2 * k + 1], s, bv[2 * k + 1]), 0.f);
      pk[k] = (u32)f2bf(o0) | ((u32)f2bf(o1) << 16);
    }
    *(uint4*)(H + (size_t)v * 128 + ch8 * 8) = make_uint4(pk[0], pk[1], pk[2], pk[3]);
  }
}

// ---------------- edge head: EDGE-CENTRIC, 32 edges per wave, perfectly balanced ----------
// UV: [NND][256] bf16 (U = cols 0..127, V+be1 = cols 128..255). sre.x = row | col<<16.
__global__ __launch_bounds__(256) void k_edge(const uint2* __restrict__ sre,
                                              const u16* __restrict__ UV,
                                              const float* __restrict__ We2,
                                              const float* __restrict__ be2, float* __restrict__ out) {
  int wid = threadIdx.x >> 6, lane = threadIdx.x & 63;
  int ch8 = lane & 15, slot = lane >> 4;
  int e0 = (blockIdx.x * 4 + wid) * 32;          // NE % 128 == 0: always full
  const uint4* UV4 = (const uint4*)UV;           // row = 32 uint4
  float w2[8];
  {
    float4 wa = *(const float4*)(We2 + ch8 * 8);
    float4 wb = *(const float4*)(We2 + ch8 * 8 + 4);
    w2[0] = wa.x; w2[1] = wa.y; w2[2] = wa.z; w2[3] = wa.w;
    w2[4] = wb.x; w2[5] = wb.y; w2[6] = wb.z; w2[7] = wb.w;
  }
  float bias2 = be2[0];
  uint2 e[8];
  #pragma unroll
  for (int u = 0; u < 8; ++u) e[u] = sre[e0 + u * 4 + slot];
  uint4 m[8];
  #pragma unroll
  for (int u = 0; u < 8; ++u) m[u] = UV4[(size_t)(e[u].x & 0xFFFFu) * 32 + ch8];
  float p[8];
  float vv[8];
  int ccur = -1;
  #pragma unroll
  for (int u = 0; u < 8; ++u) {
    int c = (int)(e[u].x >> 16);
    if (c != ccur) {                             // uniform within 16-lane group
      uint4 mv = UV4[(size_t)c * 32 + 16 + ch8];
      unpack8(mv, vv);
      ccur = c;
    }
    float f[8]; unpack8(m[u], f);
    float s0 = fmaxf(f[0] + vv[0], 0.f) * w2[0] + fmaxf(f[1] + vv[1], 0.f) * w2[1];
    s0 += fmaxf(f[2] + vv[2], 0.f) * w2[2] + fmaxf(f[3] + vv[3], 0.f) * w2[3];
    s0 += fmaxf(f[4] + vv[4], 0.f) * w2[4] + fmaxf(f[5] + vv[5], 0.f) * w2[5];
    s0 += fmaxf(f[6] + vv[6], 0.f) * w2[6] + fmaxf(f[7] + vv[7], 0.f) * w2[7];
    p[u] = s0;
  }
  #pragma unroll
  for (int off = 8; off; off >>= 1) {
    #pragma unroll
    for (int u = 0; u < 8; ++u) p[u] += __shfl_xor(p[u], off);
  }
  if (ch8 == 0) {
    #pragma unroll
    for (int u = 0; u < 8; ++u)
      out[e[u].y] = 1.f / (1.f + __expf(-(p[u] + bias2)));
  }
}

extern "C" void kernel_launch(void* const* d_in, const int* in_sizes, int n_in,
                              void* d_out, int out_size, void* d_ws, size_t ws_size,
                              hipStream_t stream) {
  const float* x   = (const float*)d_in[0];
  const int*   ei  = (const int*)d_in[1];
  const float* W1  = (const float*)d_in[2];
  const float* b1  = (const float*)d_in[3];
  const float* W2  = (const float*)d_in[4];
  const float* b2  = (const float*)d_in[5];
  const float* We1 = (const float*)d_in[6];
  const float* be1 = (const float*)d_in[7];
  const float* We2 = (const float*)d_in[8];
  const float* be2 = (const float*)d_in[9];
  float* out = (float*)d_out;

  const int* row  = ei;
  const int* colp = ei + NE;

  // ws layout (u32 units):
  // ptr[0,50064) dinv[50064,100112) bhist[100112,100308) dhist[100308,100372)
  // dcur[100372,100436) bbase[100436,100632) bcur[100632,100828) perm[100828,150828)
  // recs[150828,1750828) sre[1750828,3350828)
  // t1h[3350828,+8192) t1l t2h t2l teh(+16384) tel(+16384) -> end 3416364
  // Ts[3416364,+3.2M) H[6616364,+3.2M) UV[9816364,+6.4M) end 16216364
  if (ws_size < (size_t)16216364 * 4) return;
  int*   ptr    = (int*)d_ws;
  float* dinv   = (float*)d_ws + 50064;
  u32*   bhist  = (u32*)d_ws + 100112;
  u32*   dhist  = (u32*)d_ws + 100308;
  u32*   dcur   = (u32*)d_ws + 100372;
  u32*   bbase  = (u32*)d_ws + 100436;
  u32*   bcur   = (u32*)d_ws + 100632;
  int*   perm   = (int*)d_ws + 100828;
  uint2* recs   = (uint2*)((u32*)d_ws + 150828);
  uint2* sre    = (uint2*)((u32*)d_ws + 1750828);
  u16*   t1h    = (u16*)((u32*)d_ws + 3350828);
  u16*   t1l    = (u16*)((u32*)d_ws + 3359020);
  u16*   t2h    = (u16*)((u32*)d_ws + 3367212);
  u16*   t2l    = (u16*)((u32*)d_ws + 3375404);
  u16*   teh    = (u16*)((u32*)d_ws + 3383596);
  u16*   tel    = (u16*)((u32*)d_ws + 3399980);
  u16*   Ts     = (u16*)((u32*)d_ws + 3416364);
  u16*   H      = (u16*)((u32*)d_ws + 6616364);
  u16*   UV     = (u16*)((u32*)d_ws + 9816364);

  (void)hipMemsetAsync(bhist, 0, (NBK + 64) * sizeof(u32), stream);   // bhist + dhist
  k_prep  <<<BINB + 256, 256, 0, stream>>>(colp, bhist, W1, W2, We1, t1h, t1l, t2h, t2l, teh, tel);
  k_bscan <<<1, 256, 0, stream>>>(bhist, bbase, bcur);
  k_bin   <<<BINB, 256, 0, stream>>>(row, colp, bcur, recs);
  k_fine  <<<NBK, 256, 0, stream>>>(bhist, bbase, recs, sre, ptr, dinv, dhist);
  k_dscan <<<1, 64, 0, stream>>>(dhist, dcur);
  k_dplace<<<NBK, 256, 0, stream>>>(ptr, dcur, perm);

  int node_grid = (NND + 3) / 4;      // one node per wave64, 4 waves/block
  int edge_grid = NE / 128;           // 6250: 32 edges per wave, exact

  // layer 1: Ts = bf16((x@W1)*dinv) ; H = relu(dinv*(Ts_self + gather) + b1)
  k_mm<true><<<NCH, 512, 0, stream>>>(x, t1h, t1l, Ts, dinv, 128, nullptr);
  k_gather<<<node_grid, 256, 0, stream>>>(ptr, sre, perm, dinv, Ts, H, b1);

  // layer 2
  k_mm<false><<<NCH, 512, 0, stream>>>(H, t2h, t2l, Ts, dinv, 128, nullptr);
  k_gather<<<node_grid, 256, 0, stream>>>(ptr, sre, perm, dinv, Ts, H, b2);

  // edge head: UV = H @ [We1_top | We1_bot] (V half gets +be1 baked in), then per-edge
  k_mm<false><<<2 * NCH, 512, 0, stream>>>(H, teh, tel, UV, nullptr, 256, be1);
  k_edge<<<edge_grid, 256, 0, stream>>>(sre, UV, We2, be2, out);
}

// Round 11
// 244.116 us; speedup vs baseline: 2.1315x; 2.1315x over previous
//
#include <hip/hip_runtime.h>
#include <math.h>

#define NND 50000
#define HD  128
#define NE  800000
#define NBK 196          // buckets of 256 nodes: col>>8, max 195
#define BINB 391         // ceil(NE/2048)
#define NCH 391          // 50048/128 row chunks for k_mm

typedef unsigned short u16;
typedef unsigned int   u32;
typedef __attribute__((ext_vector_type(8))) short bf16x8;
typedef __attribute__((ext_vector_type(4))) float f32x4;

__device__ __forceinline__ float bf2f(u32 u) {
  union { u32 i; float f; } v; v.i = u << 16; return v.f;
}
__device__ __forceinline__ u16 f2bf(float f) {
  union { float f; u32 i; } v; v.f = f;
  return (u16)((v.i + 0x7FFFu + ((v.i >> 16) & 1u)) >> 16);
}
__device__ __forceinline__ void unpack8(uint4 m, float* f) {
  f[0] = bf2f(m.x & 0xFFFFu); f[1] = bf2f(m.x >> 16);
  f[2] = bf2f(m.y & 0xFFFFu); f[3] = bf2f(m.y >> 16);
  f[4] = bf2f(m.z & 0xFFFFu); f[5] = bf2f(m.z >> 16);
  f[6] = bf2f(m.w & 0xFFFFu); f[7] = bf2f(m.w >> 16);
}

// ---------------- fused: bucket histogram + weight prep ----------------
// blocks [0,BINB): histogram of col>>8. blocks [BINB,BINB+256): transposed bf16 hi/lo weights,
// LDS-swizzled layout: element (n,k) at u16-index n*128 + ((k>>3 ^ (n&7))<<3) + (k&7)
__global__ __launch_bounds__(256) void k_prep(const int* __restrict__ col, u32* __restrict__ bhist,
                                              const float* __restrict__ W1, const float* __restrict__ W2,
                                              const float* __restrict__ We1,
                                              u16* __restrict__ t1h, u16* __restrict__ t1l,
                                              u16* __restrict__ t2h, u16* __restrict__ t2l,
                                              u16* __restrict__ teh, u16* __restrict__ tel) {
  __shared__ u32 lh[NBK];
  int tid = threadIdx.x;
  if (blockIdx.x < BINB) {
    if (tid < NBK) lh[tid] = 0;
    __syncthreads();
    int e0 = blockIdx.x * 2048;
    #pragma unroll
    for (int s = 0; s < 8; ++s) {
      int e = e0 + s * 256 + tid;
      if (e < NE) atomicAdd(&lh[col[e] >> 8], 1u);
    }
    __syncthreads();
    if (tid < NBK && lh[tid]) atomicAdd(&bhist[tid], lh[tid]);
    return;
  }
  int idx = (blockIdx.x - BINB) * 256 + tid;   // 65536 total
  float w;
  u16 *dh, *dl;
  int j;
  if (idx < 16384) {
    j = idx; int n = j >> 7, k = j & 127;
    w = W1[k * 128 + n]; dh = t1h; dl = t1l;
  } else if (idx < 32768) {
    j = idx - 16384; int n = j >> 7, k = j & 127;
    w = W2[k * 128 + n]; dh = t2h; dl = t2l;
  } else {
    j = idx - 32768; int n = j >> 7, k = j & 127;
    w = (n < 128) ? We1[k * 128 + n] : We1[(128 + k) * 128 + (n - 128)];
    dh = teh; dl = tel;
  }
  int n = j >> 7, k = j & 127;
  int sidx = n * 128 + ((((k >> 3) ^ (n & 7))) << 3) + (k & 7);
  u16 hi = f2bf(w);
  float res = w - bf2f((u32)hi);
  dh[sidx] = hi;
  dl[sidx] = f2bf(res);
}

// ---------------- scan bucket counts -> bbase, bcur ----------------
__global__ __launch_bounds__(256) void k_bscan(const u32* __restrict__ bhist, u32* __restrict__ bbase,
                                               u32* __restrict__ bcur) {
  __shared__ u32 ws[4];
  int tid = threadIdx.x, lane = tid & 63, wid = tid >> 6;
  u32 d = (tid < NBK) ? bhist[tid] : 0;
  u32 x = d;
  #pragma unroll
  for (int off = 1; off < 64; off <<= 1) {
    u32 y = __shfl_up(x, off);
    if (lane >= off) x += y;
  }
  if (lane == 63) ws[wid] = x;
  __syncthreads();
  u32 woff = 0;
  for (int w = 0; w < wid; ++w) woff += ws[w];
  if (tid < NBK) { bbase[tid] = woff + x - d; bcur[tid] = woff + x - d; }
}

// ---------------- binning: block-aggregated contiguous reservations per bucket --------
// record: x = row | ((col&255)<<16), y = eid
__global__ __launch_bounds__(256) void k_bin(const int* __restrict__ row, const int* __restrict__ col,
                                             u32* __restrict__ bcur, uint2* __restrict__ recs) {
  __shared__ u32 lcount[NBK], lbase[NBK];
  int tid = threadIdx.x;
  if (tid < NBK) lcount[tid] = 0;
  __syncthreads();
  int e0 = blockIdx.x * 2048;
  u32 rank[8]; int cv[8];
  #pragma unroll
  for (int s = 0; s < 8; ++s) {
    int e = e0 + s * 256 + tid;
    if (e < NE) {
      cv[s] = col[e];
      rank[s] = atomicAdd(&lcount[cv[s] >> 8], 1u);
    }
  }
  __syncthreads();
  if (tid < NBK && lcount[tid]) lbase[tid] = atomicAdd(&bcur[tid], lcount[tid]);
  __syncthreads();
  #pragma unroll
  for (int s = 0; s < 8; ++s) {
    int e = e0 + s * 256 + tid;
    if (e < NE) {
      int c = cv[s];
      u32 slot = lbase[c >> 8] + rank[s];
      recs[slot] = make_uint2((u32)row[e] | (((u32)c & 255u) << 16), (u32)e);
    }
  }
}

// ---------------- fine sort within bucket; emits sre (row | col<<16, eid), ptr, dinv ------
__global__ __launch_bounds__(256) void k_fine(const u32* __restrict__ bhist, const u32* __restrict__ bbase,
                                              const uint2* __restrict__ recs, uint2* __restrict__ sre,
                                              int* __restrict__ ptr, float* __restrict__ dinv) {
  __shared__ u32 lh[256];
  __shared__ u32 ws[4];
  int b = blockIdx.x, tid = threadIdx.x, lane = tid & 63, wid = tid >> 6;
  u32 base = bbase[b], cnt = bhist[b];
  lh[tid] = 0;
  __syncthreads();
  for (u32 i = tid; i < cnt; i += 256) atomicAdd(&lh[(recs[base + i].x >> 16) & 255u], 1u);
  __syncthreads();
  u32 ci = lh[tid];
  u32 x = ci;
  #pragma unroll
  for (int off = 1; off < 64; off <<= 1) {
    u32 y = __shfl_up(x, off);
    if (lane >= off) x += y;
  }
  if (lane == 63) ws[wid] = x;
  __syncthreads();
  u32 woff = 0;
  for (int w = 0; w < wid; ++w) woff += ws[w];
  u32 excl = woff + x - ci;
  int node = b * 256 + tid;
  if (node <= NND) ptr[node] = (int)(base + excl);
  if (node < NND) dinv[node] = rsqrtf((float)(ci + 1));
  __syncthreads();
  lh[tid] = excl;                 // cursors
  __syncthreads();
  for (u32 i = tid; i < cnt; i += 256) {
    uint2 rec = recs[base + i];
    u32 cidx = (rec.x >> 16) & 255u;
    u32 r = atomicAdd(&lh[cidx], 1u);
    sre[base + r] = make_uint2((rec.x & 0xFFFFu) | (((u32)b * 256u + cidx) << 16), rec.y);
  }
}

// ---------------- degree histogram, block-aggregated (Guideline 12!) ----------------
__global__ __launch_bounds__(256) void k_dhist(const int* __restrict__ ptr, u32* __restrict__ dhist) {
  __shared__ u32 lh[64];
  int tid = threadIdx.x;
  if (tid < 64) lh[tid] = 0;
  __syncthreads();
  int v = blockIdx.x * 256 + tid;
  if (v < NND) {
    int d = ptr[v + 1] - ptr[v];
    atomicAdd(&lh[d < 63 ? d : 63], 1u);
  }
  __syncthreads();
  if (tid < 64 && lh[tid]) atomicAdd(&dhist[tid], lh[tid]);
}

// ---------------- degree-bin suffix scan (descending degree order) ----------------
__global__ __launch_bounds__(64) void k_dscan(const u32* __restrict__ dhist, u32* __restrict__ dcur) {
  int lane = threadIdx.x;                // 0..63
  u32 d = dhist[lane];
  u32 x = d;
  #pragma unroll
  for (int off = 1; off < 64; off <<= 1) {
    u32 y = __shfl_down(x, off);
    if (lane + off < 64) x += y;
  }
  dcur[lane] = x - d;                    // start = sum of higher-degree bins
}

// ---------------- perm: nodes in descending-degree-bin order, block-aggregated ----------
__global__ __launch_bounds__(256) void k_dplace(const int* __restrict__ ptr, u32* __restrict__ dcur,
                                                int* __restrict__ perm) {
  __shared__ u32 lcount[64], lbase[64];
  int tid = threadIdx.x;
  if (tid < 64) lcount[tid] = 0;
  __syncthreads();
  int v = blockIdx.x * 256 + tid;
  int b = 0; u32 rank = 0;
  if (v < NND) {
    int d = ptr[v + 1] - ptr[v];
    b = d < 63 ? d : 63;
    rank = atomicAdd(&lcount[b], 1u);
  }
  __syncthreads();
  if (tid < 64 && lcount[tid]) lbase[tid] = atomicAdd(&dcur[tid], lcount[tid]);
  __syncthreads();
  if (v < NND) perm[lbase[b] + rank] = v;
}

// ---------------- persistent-W MFMA GEMM, one 128-row chunk per block ----------------
// OUT[r][h*128+n] = bf16( (X[r][:] . Wt_h[n][:]) * (scale?scale[r]:1) + (bias&&h ? bias[n] : 0) )
__device__ __forceinline__ void mm_body(const void* Xv, bool afp32,
                                        const u16* Whi, const u16* Wlo,
                                        u16* OUT, const float* scale, int ostride,
                                        const float* bias) {
  __shared__ __align__(16) u16 Bh[128 * 128];   // 32 KB
  __shared__ __align__(16) u16 Bl[128 * 128];   // 32 KB
  int tid = threadIdx.x;
  int h = blockIdx.x / NCH;
  int chunk = blockIdx.x - h * NCH;
  Whi += (size_t)h * 128 * 128;
  Wlo += (size_t)h * 128 * 128;
  int ooff = h * 128;
  {
    const uint4* gh = (const uint4*)Whi;
    const uint4* gl = (const uint4*)Wlo;
    uint4* lh = (uint4*)Bh;
    uint4* ll = (uint4*)Bl;
    #pragma unroll
    for (int i = 0; i < 4; ++i) {
      lh[tid + i * 512] = gh[tid + i * 512];
      ll[tid + i * 512] = gl[tid + i * 512];
    }
  }
  __syncthreads();
  int wid = tid >> 6, lane = tid & 63;
  int m16 = lane & 15, kg = lane >> 4;
  int arow = chunk * 128 + wid * 16 + m16;
  int ar = (arow < NND) ? arow : NND - 1;        // clamp: garbage stays in unstored D rows
  bf16x8 afrag[4];
  if (afp32) {
    const float* X = (const float*)Xv + (size_t)ar * 128 + kg * 8;
    #pragma unroll
    for (int ks = 0; ks < 4; ++ks) {
      float4 a = *(const float4*)(X + ks * 32);
      float4 b = *(const float4*)(X + ks * 32 + 4);
      union { u32 w[4]; bf16x8 v; } u;
      u.w[0] = (u32)f2bf(a.x) | ((u32)f2bf(a.y) << 16);
      u.w[1] = (u32)f2bf(a.z) | ((u32)f2bf(a.w) << 16);
      u.w[2] = (u32)f2bf(b.x) | ((u32)f2bf(b.y) << 16);
      u.w[3] = (u32)f2bf(b.z) | ((u32)f2bf(b.w) << 16);
      afrag[ks] = u.v;
    }
  } else {
    const u16* X = (const u16*)Xv + (size_t)ar * 128 + kg * 8;
    #pragma unroll
    for (int ks = 0; ks < 4; ++ks) afrag[ks] = *(const bf16x8*)(X + ks * 32);
  }
  int crow0 = chunk * 128 + wid * 16 + kg * 4;   // C/D: row=(lane>>4)*4+reg, col=lane&15
  float sc[4];
  #pragma unroll
  for (int j = 0; j < 4; ++j)
    sc[j] = (scale != nullptr && crow0 + j < NND) ? scale[crow0 + j] : 1.0f;
  #pragma unroll
  for (int t = 0; t < 8; ++t) {
    int coln = t * 16 + m16;
    float badd = (bias != nullptr && h != 0) ? bias[coln] : 0.f;
    f32x4 acc = {0.f, 0.f, 0.f, 0.f};
    #pragma unroll
    for (int ks = 0; ks < 4; ++ks) {
      int c8 = (ks * 4 + kg) ^ (coln & 7);
      bf16x8 bhf = *(const bf16x8*)(Bh + coln * 128 + c8 * 8);
      bf16x8 blf = *(const bf16x8*)(Bl + coln * 128 + c8 * 8);
      acc = __builtin_amdgcn_mfma_f32_16x16x32_bf16(afrag[ks], bhf, acc, 0, 0, 0);
      acc = __builtin_amdgcn_mfma_f32_16x16x32_bf16(afrag[ks], blf, acc, 0, 0, 0);
    }
    #pragma unroll
    for (int j = 0; j < 4; ++j) {
      int r = crow0 + j;
      if (r < NND) OUT[(size_t)r * ostride + ooff + coln] = f2bf(acc[j] * sc[j] + badd);
    }
  }
}

template<bool AFP32>
__global__ __launch_bounds__(512) void k_mm(const void* __restrict__ Xv,
                                            const u16* __restrict__ Whi, const u16* __restrict__ Wlo,
                                            u16* __restrict__ OUT, const float* __restrict__ scale,
                                            int ostride, const float* __restrict__ bias) {
  mm_body(Xv, AFP32, Whi, Wlo, OUT, scale, ostride, bias);
}

// ---------------- gather-aggregate: one NODE per wave64 (degree-sorted perm order) ----------
__global__ __launch_bounds__(256) void k_gather(const int* __restrict__ ptr, const uint2* __restrict__ sre,
                                                const int* __restrict__ perm,
                                                const float* __restrict__ dinv, const u16* __restrict__ Ts,
                                                u16* __restrict__ H, const float* __restrict__ bias) {
  int wid = threadIdx.x >> 6, lane = threadIdx.x & 63;
  int ch8 = lane & 15, slot = lane >> 4;
  int idx = blockIdx.x * 4 + wid; if (idx >= NND) return;
  int v = perm[idx];
  int p0 = ptr[v], p1 = ptr[v + 1];
  const uint4* T4 = (const uint4*)Ts;            // row = 16 uint4
  float acc[8];
  if (slot == 0) {
    uint4 m = T4[(size_t)v * 16 + ch8];          // self-loop (Ts pre-scaled by dinv[src])
    unpack8(m, acc);
  } else {
    #pragma unroll
    for (int k = 0; k < 8; ++k) acc[k] = 0.f;
  }
  for (int j2 = p0; j2 < p1; j2 += 32) {
    bool ok[8]; int r[8];
    #pragma unroll
    for (int u = 0; u < 8; ++u) {
      int j = j2 + u * 4 + slot;
      ok[u] = j < p1;
      r[u] = (int)(sre[ok[u] ? j : p0].x & 0xFFFFu);
    }
    uint4 m[8];
    #pragma unroll
    for (int u = 0; u < 8; ++u) m[u] = T4[(size_t)r[u] * 16 + ch8];
    #pragma unroll
    for (int u = 0; u < 8; ++u) {
      if (ok[u]) {
        float f[8]; unpack8(m[u], f);
        #pragma unroll
        for (int k = 0; k < 8; ++k) acc[k] += f[k];
      }
    }
  }
  #pragma unroll
  for (int k = 0; k < 8; ++k) {
    acc[k] += __shfl_xor(acc[k], 16);
    acc[k] += __shfl_xor(acc[k], 32);
  }
  if (slot == 0) {
    float s = dinv[v];
    float4 ba = *(const float4*)(bias + ch8 * 8);
    float4 bb = *(const float4*)(bias + ch8 * 8 + 4);
    float bv[8] = {ba.x, ba.y, ba.z, ba.w, bb.x, bb.y, bb.z, bb.w};
    u32 pk[4];
    #pragma unroll
    for (int k = 0; k < 4; ++k) {
      float o0 = fmaxf(fmaf(acc[2 * k], s, bv[2 * k]), 0.f);
      float o1 = fmaxf(fmaf(acc[2 * k + 1], s, bv[2 * k + 1]), 0.f);
      pk[k] = (u32)f2bf(o0) | ((u32)f2bf(o1) << 16);
    }
    *(uint4*)(H + (size_t)v * 128 + ch8 * 8) = make_uint4(pk[0], pk[1], pk[2], pk[3]);
  }
}

// ---------------- edge head: EDGE-CENTRIC, 32 edges per wave, perfectly balanced ----------
// UV: [NND][256] bf16 (U = cols 0..127, V+be1 = cols 128..255). sre.x = row | col<<16.
__global__ __launch_bounds__(256) void k_edge(const uint2* __restrict__ sre,
                                              const u16* __restrict__ UV,
                                              const float* __restrict__ We2,
                                              const float* __restrict__ be2, float* __restrict__ out) {
  int wid = threadIdx.x >> 6, lane = threadIdx.x & 63;
  int ch8 = lane & 15, slot = lane >> 4;
  int e0 = (blockIdx.x * 4 + wid) * 32;          // NE % 128 == 0: always full
  const uint4* UV4 = (const uint4*)UV;           // row = 32 uint4
  float w2[8];
  {
    float4 wa = *(const float4*)(We2 + ch8 * 8);
    float4 wb = *(const float4*)(We2 + ch8 * 8 + 4);
    w2[0] = wa.x; w2[1] = wa.y; w2[2] = wa.z; w2[3] = wa.w;
    w2[4] = wb.x; w2[5] = wb.y; w2[6] = wb.z; w2[7] = wb.w;
  }
  float bias2 = be2[0];
  uint2 e[8];
  #pragma unroll
  for (int u = 0; u < 8; ++u) e[u] = sre[e0 + u * 4 + slot];
  uint4 m[8];
  #pragma unroll
  for (int u = 0; u < 8; ++u) m[u] = UV4[(size_t)(e[u].x & 0xFFFFu) * 32 + ch8];
  float p[8];
  float vv[8];
  int ccur = -1;
  #pragma unroll
  for (int u = 0; u < 8; ++u) {
    int c = (int)(e[u].x >> 16);
    if (c != ccur) {                             // uniform within 16-lane group
      uint4 mv = UV4[(size_t)c * 32 + 16 + ch8];
      unpack8(mv, vv);
      ccur = c;
    }
    float f[8]; unpack8(m[u], f);
    float s0 = fmaxf(f[0] + vv[0], 0.f) * w2[0] + fmaxf(f[1] + vv[1], 0.f) * w2[1];
    s0 += fmaxf(f[2] + vv[2], 0.f) * w2[2] + fmaxf(f[3] + vv[3], 0.f) * w2[3];
    s0 += fmaxf(f[4] + vv[4], 0.f) * w2[4] + fmaxf(f[5] + vv[5], 0.f) * w2[5];
    s0 += fmaxf(f[6] + vv[6], 0.f) * w2[6] + fmaxf(f[7] + vv[7], 0.f) * w2[7];
    p[u] = s0;
  }
  #pragma unroll
  for (int off = 8; off; off >>= 1) {
    #pragma unroll
    for (int u = 0; u < 8; ++u) p[u] += __shfl_xor(p[u], off);
  }
  if (ch8 == 0) {
    #pragma unroll
    for (int u = 0; u < 8; ++u)
      out[e[u].y] = 1.f / (1.f + __expf(-(p[u] + bias2)));
  }
}

extern "C" void kernel_launch(void* const* d_in, const int* in_sizes, int n_in,
                              void* d_out, int out_size, void* d_ws, size_t ws_size,
                              hipStream_t stream) {
  const float* x   = (const float*)d_in[0];
  const int*   ei  = (const int*)d_in[1];
  const float* W1  = (const float*)d_in[2];
  const float* b1  = (const float*)d_in[3];
  const float* W2  = (const float*)d_in[4];
  const float* b2  = (const float*)d_in[5];
  const float* We1 = (const float*)d_in[6];
  const float* be1 = (const float*)d_in[7];
  const float* We2 = (const float*)d_in[8];
  const float* be2 = (const float*)d_in[9];
  float* out = (float*)d_out;

  const int* row  = ei;
  const int* colp = ei + NE;

  // ws layout (u32 units):
  // ptr[0,50064) dinv[50064,100112) bhist[100112,100308) dhist[100308,100372)
  // dcur[100372,100436) bbase[100436,100632) bcur[100632,100828) perm[100828,150828)
  // recs[150828,1750828) sre[1750828,3350828)
  // t1h[3350828,+8192) t1l t2h t2l teh(+16384) tel(+16384) -> end 3416364
  // Ts[3416364,+3.2M) H[6616364,+3.2M) UV[9816364,+6.4M) end 16216364
  if (ws_size < (size_t)16216364 * 4) return;
  int*   ptr    = (int*)d_ws;
  float* dinv   = (float*)d_ws + 50064;
  u32*   bhist  = (u32*)d_ws + 100112;
  u32*   dhist  = (u32*)d_ws + 100308;
  u32*   dcur   = (u32*)d_ws + 100372;
  u32*   bbase  = (u32*)d_ws + 100436;
  u32*   bcur   = (u32*)d_ws + 100632;
  int*   perm   = (int*)d_ws + 100828;
  uint2* recs   = (uint2*)((u32*)d_ws + 150828);
  uint2* sre    = (uint2*)((u32*)d_ws + 1750828);
  u16*   t1h    = (u16*)((u32*)d_ws + 3350828);
  u16*   t1l    = (u16*)((u32*)d_ws + 3359020);
  u16*   t2h    = (u16*)((u32*)d_ws + 3367212);
  u16*   t2l    = (u16*)((u32*)d_ws + 3375404);
  u16*   teh    = (u16*)((u32*)d_ws + 3383596);
  u16*   tel    = (u16*)((u32*)d_ws + 3399980);
  u16*   Ts     = (u16*)((u32*)d_ws + 3416364);
  u16*   H      = (u16*)((u32*)d_ws + 6616364);
  u16*   UV     = (u16*)((u32*)d_ws + 9816364);

  (void)hipMemsetAsync(bhist, 0, (NBK + 64) * sizeof(u32), stream);   // bhist + dhist
  k_prep  <<<BINB + 256, 256, 0, stream>>>(colp, bhist, W1, W2, We1, t1h, t1l, t2h, t2l, teh, tel);
  k_bscan <<<1, 256, 0, stream>>>(bhist, bbase, bcur);
  k_bin   <<<BINB, 256, 0, stream>>>(row, colp, bcur, recs);
  k_fine  <<<NBK, 256, 0, stream>>>(bhist, bbase, recs, sre, ptr, dinv);
  k_dhist <<<NBK, 256, 0, stream>>>(ptr, dhist);
  k_dscan <<<1, 64, 0, stream>>>(dhist, dcur);
  k_dplace<<<NBK, 256, 0, stream>>>(ptr, dcur, perm);

  int node_grid = (NND + 3) / 4;      // one node per wave64, 4 waves/block
  int edge_grid = NE / 128;           // 6250: 32 edges per wave, exact

  // layer 1: Ts = bf16((x@W1)*dinv) ; H = relu(dinv*(Ts_self + gather) + b1)
  k_mm<true><<<NCH, 512, 0, stream>>>(x, t1h, t1l, Ts, dinv, 128, nullptr);
  k_gather<<<node_grid, 256, 0, stream>>>(ptr, sre, perm, dinv, Ts, H, b1);

  // layer 2
  k_mm<false><<<NCH, 512, 0, stream>>>(H, t2h, t2l, Ts, dinv, 128, nullptr);
  k_gather<<<node_grid, 256, 0, stream>>>(ptr, sre, perm, dinv, Ts, H, b2);

  // edge head: UV = H @ [We1_top | We1_bot] (V half gets +be1 baked in), then per-edge
  k_mm<false><<<2 * NCH, 512, 0, stream>>>(H, teh, tel, UV, nullptr, 256, be1);
  k_edge<<<edge_grid, 256, 0, stream>>>(sre, UV, We2, be2, out);
}

// Round 12
// 205.959 us; speedup vs baseline: 2.5264x; 1.1853x over previous
//
#include <hip/hip_runtime.h>
#include <math.h>

#define NND 50000
#define HD  128
#define NE  800000
#define NBK 196          // buckets of 256 nodes: col>>8, max 195
#define BINB 391         // ceil(NE/2048)
#define NCH 391          // 50048/128 row chunks for k_mm

typedef unsigned short u16;
typedef unsigned int   u32;
typedef __attribute__((ext_vector_type(8))) short bf16x8;
typedef __attribute__((ext_vector_type(4))) float f32x4;

__device__ __forceinline__ float bf2f(u32 u) {
  union { u32 i; float f; } v; v.i = u << 16; return v.f;
}
__device__ __forceinline__ u16 f2bf(float f) {
  union { float f; u32 i; } v; v.f = f;
  return (u16)((v.i + 0x7FFFu + ((v.i >> 16) & 1u)) >> 16);
}
__device__ __forceinline__ void unpack8(uint4 m, float* f) {
  f[0] = bf2f(m.x & 0xFFFFu); f[1] = bf2f(m.x >> 16);
  f[2] = bf2f(m.y & 0xFFFFu); f[3] = bf2f(m.y >> 16);
  f[4] = bf2f(m.z & 0xFFFFu); f[5] = bf2f(m.z >> 16);
  f[6] = bf2f(m.w & 0xFFFFu); f[7] = bf2f(m.w >> 16);
}

// ---------------- fused: bucket histogram + weight prep ----------------
// blocks [0,BINB): histogram of col>>8. blocks [BINB,BINB+256): transposed bf16 hi/lo weights,
// LDS-swizzled layout: element (n,k) at u16-index n*128 + ((k>>3 ^ (n&7))<<3) + (k&7)
__global__ __launch_bounds__(256) void k_prep(const int* __restrict__ col, u32* __restrict__ bhist,
                                              const float* __restrict__ W1, const float* __restrict__ W2,
                                              const float* __restrict__ We1,
                                              u16* __restrict__ t1h, u16* __restrict__ t1l,
                                              u16* __restrict__ t2h, u16* __restrict__ t2l,
                                              u16* __restrict__ teh, u16* __restrict__ tel) {
  __shared__ u32 lh[NBK];
  int tid = threadIdx.x;
  if (blockIdx.x < BINB) {
    if (tid < NBK) lh[tid] = 0;
    __syncthreads();
    int e0 = blockIdx.x * 2048;
    #pragma unroll
    for (int s = 0; s < 8; ++s) {
      int e = e0 + s * 256 + tid;
      if (e < NE) atomicAdd(&lh[col[e] >> 8], 1u);
    }
    __syncthreads();
    if (tid < NBK && lh[tid]) atomicAdd(&bhist[tid], lh[tid]);
    return;
  }
  int idx = (blockIdx.x - BINB) * 256 + tid;   // 65536 total
  float w;
  u16 *dh, *dl;
  int j;
  if (idx < 16384) {
    j = idx; int n = j >> 7, k = j & 127;
    w = W1[k * 128 + n]; dh = t1h; dl = t1l;
  } else if (idx < 32768) {
    j = idx - 16384; int n = j >> 7, k = j & 127;
    w = W2[k * 128 + n]; dh = t2h; dl = t2l;
  } else {
    j = idx - 32768; int n = j >> 7, k = j & 127;
    w = (n < 128) ? We1[k * 128 + n] : We1[(128 + k) * 128 + (n - 128)];
    dh = teh; dl = tel;
  }
  int n = j >> 7, k = j & 127;
  int sidx = n * 128 + ((((k >> 3) ^ (n & 7))) << 3) + (k & 7);
  u16 hi = f2bf(w);
  float res = w - bf2f((u32)hi);
  dh[sidx] = hi;
  dl[sidx] = f2bf(res);
}

// ---------------- scan bucket counts -> bbase, bcur ----------------
__global__ __launch_bounds__(256) void k_bscan(const u32* __restrict__ bhist, u32* __restrict__ bbase,
                                               u32* __restrict__ bcur) {
  __shared__ u32 ws[4];
  int tid = threadIdx.x, lane = tid & 63, wid = tid >> 6;
  u32 d = (tid < NBK) ? bhist[tid] : 0;
  u32 x = d;
  #pragma unroll
  for (int off = 1; off < 64; off <<= 1) {
    u32 y = __shfl_up(x, off);
    if (lane >= off) x += y;
  }
  if (lane == 63) ws[wid] = x;
  __syncthreads();
  u32 woff = 0;
  for (int w = 0; w < wid; ++w) woff += ws[w];
  if (tid < NBK) { bbase[tid] = woff + x - d; bcur[tid] = woff + x - d; }
}

// ---------------- binning: block-aggregated contiguous reservations per bucket --------
// record: x = row | ((col&255)<<16), y = eid
__global__ __launch_bounds__(256) void k_bin(const int* __restrict__ row, const int* __restrict__ col,
                                             u32* __restrict__ bcur, uint2* __restrict__ recs) {
  __shared__ u32 lcount[NBK], lbase[NBK];
  int tid = threadIdx.x;
  if (tid < NBK) lcount[tid] = 0;
  __syncthreads();
  int e0 = blockIdx.x * 2048;
  u32 rank[8]; int cv[8];
  #pragma unroll
  for (int s = 0; s < 8; ++s) {
    int e = e0 + s * 256 + tid;
    if (e < NE) {
      cv[s] = col[e];
      rank[s] = atomicAdd(&lcount[cv[s] >> 8], 1u);
    }
  }
  __syncthreads();
  if (tid < NBK && lcount[tid]) lbase[tid] = atomicAdd(&bcur[tid], lcount[tid]);
  __syncthreads();
  #pragma unroll
  for (int s = 0; s < 8; ++s) {
    int e = e0 + s * 256 + tid;
    if (e < NE) {
      int c = cv[s];
      u32 slot = lbase[c >> 8] + rank[s];
      recs[slot] = make_uint2((u32)row[e] | (((u32)c & 255u) << 16), (u32)e);
    }
  }
}

// ---------------- fine sort within bucket; emits sre (row, eid), ptr, dinv ----------------
__global__ __launch_bounds__(256) void k_fine(const u32* __restrict__ bhist, const u32* __restrict__ bbase,
                                              const uint2* __restrict__ recs, uint2* __restrict__ sre,
                                              int* __restrict__ ptr, float* __restrict__ dinv) {
  __shared__ u32 lh[256];
  __shared__ u32 ws[4];
  int b = blockIdx.x, tid = threadIdx.x, lane = tid & 63, wid = tid >> 6;
  u32 base = bbase[b], cnt = bhist[b];
  lh[tid] = 0;
  __syncthreads();
  for (u32 i = tid; i < cnt; i += 256) atomicAdd(&lh[(recs[base + i].x >> 16) & 255u], 1u);
  __syncthreads();
  u32 ci = lh[tid];
  u32 x = ci;
  #pragma unroll
  for (int off = 1; off < 64; off <<= 1) {
    u32 y = __shfl_up(x, off);
    if (lane >= off) x += y;
  }
  if (lane == 63) ws[wid] = x;
  __syncthreads();
  u32 woff = 0;
  for (int w = 0; w < wid; ++w) woff += ws[w];
  u32 excl = woff + x - ci;
  int node = b * 256 + tid;
  if (node <= NND) ptr[node] = (int)(base + excl);
  if (node < NND) dinv[node] = rsqrtf((float)(ci + 1));
  __syncthreads();
  lh[tid] = excl;                 // cursors
  __syncthreads();
  for (u32 i = tid; i < cnt; i += 256) {
    uint2 rec = recs[base + i];
    u32 r = atomicAdd(&lh[(rec.x >> 16) & 255u], 1u);
    sre[base + r] = make_uint2(rec.x & 0xFFFFu, rec.y);
  }
}

// ---------------- persistent-W MFMA GEMM, one 128-row chunk per block ----------------
// OUT[r][h*128+n] = bf16( (X[r][:] . Wt_h[n][:]) * (scale?scale[r]:1) + (bias&&h ? bias[n] : 0) )
__device__ __forceinline__ void mm_body(const void* Xv, bool afp32,
                                        const u16* Whi, const u16* Wlo,
                                        u16* OUT, const float* scale, int ostride,
                                        const float* bias) {
  __shared__ __align__(16) u16 Bh[128 * 128];   // 32 KB
  __shared__ __align__(16) u16 Bl[128 * 128];   // 32 KB
  int tid = threadIdx.x;
  int h = blockIdx.x / NCH;
  int chunk = blockIdx.x - h * NCH;
  Whi += (size_t)h * 128 * 128;
  Wlo += (size_t)h * 128 * 128;
  int ooff = h * 128;
  {
    const uint4* gh = (const uint4*)Whi;
    const uint4* gl = (const uint4*)Wlo;
    uint4* lh = (uint4*)Bh;
    uint4* ll = (uint4*)Bl;
    #pragma unroll
    for (int i = 0; i < 4; ++i) {
      lh[tid + i * 512] = gh[tid + i * 512];
      ll[tid + i * 512] = gl[tid + i * 512];
    }
  }
  __syncthreads();
  int wid = tid >> 6, lane = tid & 63;
  int m16 = lane & 15, kg = lane >> 4;
  int arow = chunk * 128 + wid * 16 + m16;
  int ar = (arow < NND) ? arow : NND - 1;        // clamp: garbage stays in unstored D rows
  bf16x8 afrag[4];
  if (afp32) {
    const float* X = (const float*)Xv + (size_t)ar * 128 + kg * 8;
    #pragma unroll
    for (int ks = 0; ks < 4; ++ks) {
      float4 a = *(const float4*)(X + ks * 32);
      float4 b = *(const float4*)(X + ks * 32 + 4);
      union { u32 w[4]; bf16x8 v; } u;
      u.w[0] = (u32)f2bf(a.x) | ((u32)f2bf(a.y) << 16);
      u.w[1] = (u32)f2bf(a.z) | ((u32)f2bf(a.w) << 16);
      u.w[2] = (u32)f2bf(b.x) | ((u32)f2bf(b.y) << 16);
      u.w[3] = (u32)f2bf(b.z) | ((u32)f2bf(b.w) << 16);
      afrag[ks] = u.v;
    }
  } else {
    const u16* X = (const u16*)Xv + (size_t)ar * 128 + kg * 8;
    #pragma unroll
    for (int ks = 0; ks < 4; ++ks) afrag[ks] = *(const bf16x8*)(X + ks * 32);
  }
  int crow0 = chunk * 128 + wid * 16 + kg * 4;   // C/D: row=(lane>>4)*4+reg, col=lane&15
  float sc[4];
  #pragma unroll
  for (int j = 0; j < 4; ++j)
    sc[j] = (scale != nullptr && crow0 + j < NND) ? scale[crow0 + j] : 1.0f;
  #pragma unroll
  for (int t = 0; t < 8; ++t) {
    int coln = t * 16 + m16;
    float badd = (bias != nullptr && h != 0) ? bias[coln] : 0.f;
    f32x4 acc = {0.f, 0.f, 0.f, 0.f};
    #pragma unroll
    for (int ks = 0; ks < 4; ++ks) {
      int c8 = (ks * 4 + kg) ^ (coln & 7);
      bf16x8 bhf = *(const bf16x8*)(Bh + coln * 128 + c8 * 8);
      bf16x8 blf = *(const bf16x8*)(Bl + coln * 128 + c8 * 8);
      acc = __builtin_amdgcn_mfma_f32_16x16x32_bf16(afrag[ks], bhf, acc, 0, 0, 0);
      acc = __builtin_amdgcn_mfma_f32_16x16x32_bf16(afrag[ks], blf, acc, 0, 0, 0);
    }
    #pragma unroll
    for (int j = 0; j < 4; ++j) {
      int r = crow0 + j;
      if (r < NND) OUT[(size_t)r * ostride + ooff + coln] = f2bf(acc[j] * sc[j] + badd);
    }
  }
}

template<bool AFP32>
__global__ __launch_bounds__(512) void k_mm(const void* __restrict__ Xv,
                                            const u16* __restrict__ Whi, const u16* __restrict__ Wlo,
                                            u16* __restrict__ OUT, const float* __restrict__ scale,
                                            int ostride, const float* __restrict__ bias) {
  mm_body(Xv, AFP32, Whi, Wlo, OUT, scale, ostride, bias);
}

// ---------------- gather-aggregate: one NODE per wave64, 16 lanes/edge x 8ch, 32 in flight ----
__global__ __launch_bounds__(256) void k_gather(const int* __restrict__ ptr, const uint2* __restrict__ sre,
                                                const float* __restrict__ dinv, const u16* __restrict__ Ts,
                                                u16* __restrict__ H, const float* __restrict__ bias) {
  int wid = threadIdx.x >> 6, lane = threadIdx.x & 63;
  int ch8 = lane & 15, slot = lane >> 4;
  int v = blockIdx.x * 4 + wid; if (v >= NND) return;
  int p0 = ptr[v], p1 = ptr[v + 1];
  const uint4* T4 = (const uint4*)Ts;            // row = 16 uint4
  float acc[8];
  if (slot == 0) {
    uint4 m = T4[(size_t)v * 16 + ch8];          // self-loop (Ts pre-scaled by dinv[src])
    unpack8(m, acc);
  } else {
    #pragma unroll
    for (int k = 0; k < 8; ++k) acc[k] = 0.f;
  }
  for (int j2 = p0; j2 < p1; j2 += 32) {
    bool ok[8]; int r[8];
    #pragma unroll
    for (int u = 0; u < 8; ++u) {
      int j = j2 + u * 4 + slot;
      ok[u] = j < p1;
      r[u] = (int)sre[ok[u] ? j : p0].x;
    }
    uint4 m[8];
    #pragma unroll
    for (int u = 0; u < 8; ++u) m[u] = T4[(size_t)r[u] * 16 + ch8];
    #pragma unroll
    for (int u = 0; u < 8; ++u) {
      if (ok[u]) {
        float f[8]; unpack8(m[u], f);
        #pragma unroll
        for (int k = 0; k < 8; ++k) acc[k] += f[k];
      }
    }
  }
  #pragma unroll
  for (int k = 0; k < 8; ++k) {
    acc[k] += __shfl_xor(acc[k], 16);
    acc[k] += __shfl_xor(acc[k], 32);
  }
  if (slot == 0) {
    float s = dinv[v];
    float4 ba = *(const float4*)(bias + ch8 * 8);
    float4 bb = *(const float4*)(bias + ch8 * 8 + 4);
    float bv[8] = {ba.x, ba.y, ba.z, ba.w, bb.x, bb.y, bb.z, bb.w};
    u32 pk[4];
    #pragma unroll
    for (int k = 0; k < 4; ++k) {
      float o0 = fmaxf(fmaf(acc[2 * k], s, bv[2 * k]), 0.f);
      float o1 = fmaxf(fmaf(acc[2 * k + 1], s, bv[2 * k + 1]), 0.f);
      pk[k] = (u32)f2bf(o0) | ((u32)f2bf(o1) << 16);
    }
    *(uint4*)(H + (size_t)v * 128 + ch8 * 8) = make_uint4(pk[0], pk[1], pk[2], pk[3]);
  }
}

// ---------------- edge head: one NODE per wave64, 16 lanes/edge x 8ch, 32 in flight -------
// UV: [NND][256] bf16 (U = cols 0..127, V+be1 = cols 128..255, be1 prebaked by k_mm)
__global__ __launch_bounds__(256) void k_edge(const int* __restrict__ ptr, const uint2* __restrict__ sre,
                                              const u16* __restrict__ UV,
                                              const float* __restrict__ We2,
                                              const float* __restrict__ be2, float* __restrict__ out) {
  int wid = threadIdx.x >> 6, lane = threadIdx.x & 63;
  int ch8 = lane & 15, slot = lane >> 4;
  int c = blockIdx.x * 4 + wid; if (c >= NND) return;
  int p0 = ptr[c], p1 = ptr[c + 1];
  if (p0 == p1) return;
  const uint4* UV4 = (const uint4*)UV;           // row = 32 uint4
  float vv[8];
  {
    uint4 mv = UV4[(size_t)c * 32 + 16 + ch8];   // V + be1 (prebaked)
    unpack8(mv, vv);
  }
  float w2[8];
  {
    float4 wa = *(const float4*)(We2 + ch8 * 8);
    float4 wb = *(const float4*)(We2 + ch8 * 8 + 4);
    w2[0] = wa.x; w2[1] = wa.y; w2[2] = wa.z; w2[3] = wa.w;
    w2[4] = wb.x; w2[5] = wb.y; w2[6] = wb.z; w2[7] = wb.w;
  }
  float bias2 = be2[0];
  for (int j2 = p0; j2 < p1; j2 += 32) {
    bool ok[8]; uint2 e[8];
    #pragma unroll
    for (int u = 0; u < 8; ++u) {
      int j = j2 + u * 4 + slot;
      ok[u] = j < p1;
      e[u] = sre[ok[u] ? j : p0];
    }
    uint4 m[8];
    #pragma unroll
    for (int u = 0; u < 8; ++u) m[u] = UV4[(size_t)e[u].x * 32 + ch8];
    float p[8];
    #pragma unroll
    for (int u = 0; u < 8; ++u) {
      float f[8]; unpack8(m[u], f);
      float s0 = fmaxf(f[0] + vv[0], 0.f) * w2[0] + fmaxf(f[1] + vv[1], 0.f) * w2[1];
      s0 += fmaxf(f[2] + vv[2], 0.f) * w2[2] + fmaxf(f[3] + vv[3], 0.f) * w2[3];
      s0 += fmaxf(f[4] + vv[4], 0.f) * w2[4] + fmaxf(f[5] + vv[5], 0.f) * w2[5];
      s0 += fmaxf(f[6] + vv[6], 0.f) * w2[6] + fmaxf(f[7] + vv[7], 0.f) * w2[7];
      p[u] = s0;
    }
    #pragma unroll
    for (int off = 8; off; off >>= 1) {
      #pragma unroll
      for (int u = 0; u < 8; ++u) p[u] += __shfl_xor(p[u], off);
    }
    if (ch8 == 0) {
      #pragma unroll
      for (int u = 0; u < 8; ++u)
        if (ok[u]) out[e[u].y] = 1.f / (1.f + __expf(-(p[u] + bias2)));
    }
  }
}

extern "C" void kernel_launch(void* const* d_in, const int* in_sizes, int n_in,
                              void* d_out, int out_size, void* d_ws, size_t ws_size,
                              hipStream_t stream) {
  const float* x   = (const float*)d_in[0];
  const int*   ei  = (const int*)d_in[1];
  const float* W1  = (const float*)d_in[2];
  const float* b1  = (const float*)d_in[3];
  const float* W2  = (const float*)d_in[4];
  const float* b2  = (const float*)d_in[5];
  const float* We1 = (const float*)d_in[6];
  const float* be1 = (const float*)d_in[7];
  const float* We2 = (const float*)d_in[8];
  const float* be2 = (const float*)d_in[9];
  float* out = (float*)d_out;

  const int* row  = ei;
  const int* colp = ei + NE;

  // ws layout (u32 units):
  // ptr[0,50064) dinv[50064,100112) bhist[100112,100308) bbase[100308,100504) bcur[100504,100700)
  // recs[100704,1700704) sre[1700704,3300704)
  // t1h[3300704,+8192) t1l t2h t2l teh(+16384) tel(+16384)
  // Ts[3366240,+3.2M) H[6566240,+3.2M) UV[9766240,+6.4M)  end 16166240
  if (ws_size < (size_t)16166240 * 4) return;
  int*   ptr    = (int*)d_ws;
  float* dinv   = (float*)d_ws + 50064;
  u32*   bhist  = (u32*)d_ws + 100112;
  u32*   bbase  = (u32*)d_ws + 100308;
  u32*   bcur   = (u32*)d_ws + 100504;
  uint2* recs   = (uint2*)((u32*)d_ws + 100704);
  uint2* sre    = (uint2*)((u32*)d_ws + 1700704);
  u16*   t1h    = (u16*)((u32*)d_ws + 3300704);
  u16*   t1l    = (u16*)((u32*)d_ws + 3308896);
  u16*   t2h    = (u16*)((u32*)d_ws + 3317088);
  u16*   t2l    = (u16*)((u32*)d_ws + 3325280);
  u16*   teh    = (u16*)((u32*)d_ws + 3333472);
  u16*   tel    = (u16*)((u32*)d_ws + 3349856);
  u16*   Ts     = (u16*)((u32*)d_ws + 3366240);
  u16*   H      = (u16*)((u32*)d_ws + 6566240);
  u16*   UV     = (u16*)((u32*)d_ws + 9766240);

  (void)hipMemsetAsync(bhist, 0, NBK * sizeof(u32), stream);
  k_prep <<<BINB + 256, 256, 0, stream>>>(colp, bhist, W1, W2, We1, t1h, t1l, t2h, t2l, teh, tel);
  k_bscan<<<1, 256, 0, stream>>>(bhist, bbase, bcur);
  k_bin  <<<BINB, 256, 0, stream>>>(row, colp, bcur, recs);
  k_fine <<<NBK, 256, 0, stream>>>(bhist, bbase, recs, sre, ptr, dinv);

  int node_grid = (NND + 3) / 4;      // one node per wave64, 4 waves/block

  // layer 1: Ts = bf16((x@W1)*dinv) ; H = relu(dinv*(Ts_self + gather) + b1)
  k_mm<true><<<NCH, 512, 0, stream>>>(x, t1h, t1l, Ts, dinv, 128, nullptr);
  k_gather<<<node_grid, 256, 0, stream>>>(ptr, sre, dinv, Ts, H, b1);

  // layer 2
  k_mm<false><<<NCH, 512, 0, stream>>>(H, t2h, t2l, Ts, dinv, 128, nullptr);
  k_gather<<<node_grid, 256, 0, stream>>>(ptr, sre, dinv, Ts, H, b2);

  // edge head: UV = H @ [We1_top | We1_bot] (V half gets +be1 baked in), then per-edge
  k_mm<false><<<2 * NCH, 512, 0, stream>>>(H, teh, tel, UV, nullptr, 256, be1);
  k_edge<<<node_grid, 256, 0, stream>>>(ptr, sre, UV, We2, be2, out);
}